// Round 1
// baseline (591.743 us; speedup 1.0000x reference)
//
#include <hip/hip_runtime.h>
#include <math.h>

// Problem constants: B=4, C=128, O=128, H=W=128, k=3, K=9, pad=1, stride=1.
#define HWD 16384   // H*W
#define NB  4
#define NC  128
#define NO  128

// w_t[r][o], r = c*9+k  (1152 x 128)
__global__ void k_transpose_wreg(const float* __restrict__ w_reg, float* __restrict__ w_t) {
    int i = blockIdx.x * 256 + threadIdx.x;           // 147456 total
    if (i >= 1152 * 128) return;
    int o = i & 127, r = i >> 7;
    w_t[r * 128 + o] = w_reg[o * 1152 + r];           // w_reg[o][c][k] flat = o*1152 + r
}

// wt_om[(c*9+k)*27 + oc]: oc 0..17 = offset weights, 18..26 = mask weights
__global__ void k_transpose_wom(const float* __restrict__ w_off, const float* __restrict__ w_mod,
                                float* __restrict__ wt_om) {
    int i = blockIdx.x * 256 + threadIdx.x;           // 31104 total
    if (i >= 1152 * 27) return;
    int oc = i % 27, r = i / 27;
    wt_om[i] = (oc < 18) ? w_off[oc * 1152 + r] : w_mod[(oc - 18) * 1152 + r];
}

// 3x3 conv producing 27 raw channels (no bias/sigmoid; applied by consumer).
// Grid: (8, 8, B*3). Block: 256 threads = 16x16 pixel tile. oc-group = blockIdx.z%3 (9 oc each).
__global__ __launch_bounds__(256) void k_conv_om(const float* __restrict__ x,
                                                 const float* __restrict__ wt_om,
                                                 float* __restrict__ cbuf) {
    __shared__ float xt[18 * 18];
    int b  = blockIdx.z / 3;
    int og = blockIdx.z % 3;
    int ty = blockIdx.y * 16, tx = blockIdx.x * 16;
    int tid = threadIdx.x;
    int row = tid >> 4, col = tid & 15;

    float acc[9];
#pragma unroll
    for (int j = 0; j < 9; ++j) acc[j] = 0.f;

    for (int c = 0; c < NC; ++c) {
        __syncthreads();
        for (int i = tid; i < 324; i += 256) {
            int ry = i / 18, rx = i - ry * 18;
            int gy = ty - 1 + ry, gx = tx - 1 + rx;
            float v = 0.f;
            if (gy >= 0 && gy < 128 && gx >= 0 && gx < 128)
                v = x[(((b << 7) + c) << 14) + (gy << 7) + gx];
            xt[i] = v;
        }
        __syncthreads();
#pragma unroll
        for (int k = 0; k < 9; ++k) {
            float xv = xt[(row + k / 3) * 18 + (col + k % 3)];
            const float* wp = wt_om + (c * 9 + k) * 27 + og * 9;   // block-uniform -> s_load
#pragma unroll
            for (int j = 0; j < 9; ++j) acc[j] = fmaf(wp[j], xv, acc[j]);
        }
    }

    int hw = ((ty + row) << 7) + tx + col;
#pragma unroll
    for (int j = 0; j < 9; ++j) {
        int oc = og * 9 + j;
        cbuf[((b * 27 + oc) << 14) + hw] = acc[j];
    }
}

// Deformable gather + GEMM. Grid: (HW/64, B). Block: 256 threads = 4 waves.
// Wave w owns output channels [w*32, w*32+32), lane = pixel within the 64-pixel strip.
__global__ __launch_bounds__(256, 4) void k_deform(const float* __restrict__ x,
                                                   const float* __restrict__ cbuf,
                                                   const float* __restrict__ b_off,
                                                   const float* __restrict__ b_mod,
                                                   const float* __restrict__ w_t,
                                                   float* __restrict__ out) {
    __shared__ int   sp_idx[9 * 4 * 64];    // [k][corner][pixel]
    __shared__ float sp_w  [9 * 4 * 64];    // premultiplied mask*bilinear*valid
    __shared__ float lds_val[72 * 64];      // [r within chunk][pixel]

    int tid = threadIdx.x;
    int b = blockIdx.y;
    int hwbase = blockIdx.x * 64;
    int lane = tid & 63;
    int wid = tid >> 6;

    // ---- Phase 1: sample descriptors for 64 pixels x 9 taps ----
    for (int i = tid; i < 576; i += 256) {
        int k = i >> 6, p = i & 63;
        int hw = hwbase + p;
        int h = hw >> 7, cc = hw & 127;
        const float* cb = cbuf + ((size_t)(b * 27) << 14);
        float oy = cb[((2 * k) << 14) + hw]     + b_off[2 * k];
        float ox = cb[((2 * k + 1) << 14) + hw] + b_off[2 * k + 1];
        float mr = cb[((18 + k) << 14) + hw]    + b_mod[k];
        float m  = 2.f / (1.f + expf(-mr));
        float py = (float)(h - 1 + k / 3) + oy;
        float px = (float)(cc - 1 + k % 3) + ox;
        float fy = floorf(py), fx = floorf(px);
        float wy1 = py - fy, wx1 = px - fx;
        int y0 = (int)fy, x0 = (int)fx;
#pragma unroll
        for (int dy = 0; dy < 2; ++dy)
#pragma unroll
            for (int dx = 0; dx < 2; ++dx) {
                int yy = y0 + dy, xx = x0 + dx;
                bool valid = (yy >= 0) && (yy < 128) && (xx >= 0) && (xx < 128);
                float wgt = m * (dy ? wy1 : 1.f - wy1) * (dx ? wx1 : 1.f - wx1);
                int yc = min(max(yy, 0), 127), xc = min(max(xx, 0), 127);
                int s = (k * 4 + dy * 2 + dx) * 64 + p;
                sp_idx[s] = (yc << 7) + xc;
                sp_w[s]   = valid ? wgt : 0.f;
            }
    }

    float acc[32];
#pragma unroll
    for (int i = 0; i < 32; ++i) acc[i] = 0.f;

    int obase = __builtin_amdgcn_readfirstlane(wid * 32);
    int p = lane;
    int rs = wid;                      // this thread samples rows [rs*18, rs*18+18)

    for (int chunk = 0; chunk < 16; ++chunk) {
        int cbase = chunk * 8;
        __syncthreads();               // phase-1 done / previous GEMM reads done

        // ---- gather 8 channels x 9 taps into lds_val[72][64] ----
#pragma unroll 3
        for (int j = 0; j < 18; ++j) {
            int c = cbase + rs * 2 + j / 9;          // j/9, j%9 are compile-time
            int k = j % 9;
            const float* xb = x + ((size_t)(b * NC + c) << 14);
            int sb = (k * 4) * 64 + p;
            float v = sp_w[sb]       * xb[sp_idx[sb]]
                    + sp_w[sb + 64]  * xb[sp_idx[sb + 64]]
                    + sp_w[sb + 128] * xb[sp_idx[sb + 128]]
                    + sp_w[sb + 192] * xb[sp_idx[sb + 192]];
            lds_val[(rs * 18 + j) * 64 + p] = v;
        }
        __syncthreads();

        // ---- GEMM: acc[o] += w_t[cbase*9+r][obase+o] * val[r][lane] ----
        const float* wrow = w_t + (size_t)(cbase * 9) * 128 + obase;
#pragma unroll 2
        for (int r = 0; r < 72; ++r) {
            float v = lds_val[r * 64 + lane];
            const float4* w4 = (const float4*)(wrow + (size_t)r * 128);  // wave-uniform
#pragma unroll
            for (int i = 0; i < 8; ++i) {
                float4 ww = w4[i];
                acc[i * 4 + 0] = fmaf(ww.x, v, acc[i * 4 + 0]);
                acc[i * 4 + 1] = fmaf(ww.y, v, acc[i * 4 + 1]);
                acc[i * 4 + 2] = fmaf(ww.z, v, acc[i * 4 + 2]);
                acc[i * 4 + 3] = fmaf(ww.w, v, acc[i * 4 + 3]);
            }
        }
    }

    // ---- write out: coalesced 64-wide rows ----
    size_t ob = ((size_t)(b * NO + obase) << 14) + hwbase + lane;
#pragma unroll
    for (int i = 0; i < 32; ++i)
        out[ob + ((size_t)i << 14)] = acc[i];
}

extern "C" void kernel_launch(void* const* d_in, const int* in_sizes, int n_in,
                              void* d_out, int out_size, void* d_ws, size_t ws_size,
                              hipStream_t stream) {
    const float* x     = (const float*)d_in[0];
    const float* w_off = (const float*)d_in[1];
    const float* b_off = (const float*)d_in[2];
    const float* w_mod = (const float*)d_in[3];
    const float* b_mod = (const float*)d_in[4];
    const float* w_reg = (const float*)d_in[5];
    float* out = (float*)d_out;

    // workspace layout (floats): cbuf [4*27*16384] | w_t [1152*128] | wt_om [1152*27]
    float* cbuf  = (float*)d_ws;
    float* w_t   = cbuf + (size_t)NB * 27 * HWD;   // 1,769,472
    float* wt_om = w_t + 1152 * 128;               // +147,456
    // total = 7.8 MB of ws

    hipLaunchKernelGGL(k_transpose_wreg, dim3(576), dim3(256), 0, stream, w_reg, w_t);
    hipLaunchKernelGGL(k_transpose_wom,  dim3(122), dim3(256), 0, stream, w_off, w_mod, wt_om);
    hipLaunchKernelGGL(k_conv_om, dim3(8, 8, NB * 3), dim3(256), 0, stream, x, wt_om, cbuf);
    hipLaunchKernelGGL(k_deform, dim3(HWD / 64, NB), dim3(256), 0, stream,
                       x, cbuf, b_off, b_mod, w_t, out);
}